// Round 2
// baseline (506.317 us; speedup 1.0000x reference)
//
#include <hip/hip_runtime.h>
#include <math.h>

#define B_ 32
#define Q_ 16
#define D_ 10
#define L_ 1000
#define E_ 300
#define NC 75          // float4 chunks per row
#define PF 15          // prefetch depth (75 = 15*5)

// ---------------------------------------------------------------------------
// Kernel 1 (prep): gate logits -> softmax -> fused per-query weight
//   wq[b,q]   = softmax(gate_logits)[b,q] * out_w * w2
//   invNq[b,q]= 1/||emb[q_tok]||          (q rows get pre-normalized in LDS)
//   score[b,d]= out_w*(w2*b1 + b2) + out_b   (atomics add onto this)
// ---------------------------------------------------------------------------
__global__ __launch_bounds__(256) void drmm_prep(
    const int* __restrict__ bq, const float* __restrict__ emb,
    const float* __restrict__ gate_w, const float* __restrict__ gate_b,
    const float* __restrict__ b1, const float* __restrict__ w2,
    const float* __restrict__ b2, const float* __restrict__ out_w,
    const float* __restrict__ out_b,
    float* __restrict__ wqBuf, float* __restrict__ invNqBuf,
    float* __restrict__ score)
{
    const int b = blockIdx.x;
    const int tid = threadIdx.x;
    const int w = tid >> 6, lane = tid & 63;
    __shared__ float logits[Q_];

#pragma unroll
    for (int i = 0; i < 4; ++i) {
        const int q = w * 4 + i;                  // 4 waves x 4 -> q = 0..15
        const int tok = bq[b * Q_ + q];
        const float* row = emb + (size_t)tok * E_;
        float4 dv = *(const float4*)(row + 4 * lane);
        float4 gv = *(const float4*)(gate_w + 4 * lane);
        float pd = dv.x * gv.x + dv.y * gv.y + dv.z * gv.z + dv.w * gv.w;
        float ps = dv.x * dv.x + dv.y * dv.y + dv.z * dv.z + dv.w * dv.w;
        if (lane < 11) {
            float4 dv2 = *(const float4*)(row + 256 + 4 * lane);
            float4 gv2 = *(const float4*)(gate_w + 256 + 4 * lane);
            pd += dv2.x * gv2.x + dv2.y * gv2.y + dv2.z * gv2.z + dv2.w * gv2.w;
            ps += dv2.x * dv2.x + dv2.y * dv2.y + dv2.z * dv2.z + dv2.w * dv2.w;
        }
#pragma unroll
        for (int off = 32; off > 0; off >>= 1) {
            pd += __shfl_xor(pd, off);
            ps += __shfl_xor(ps, off);
        }
        if (lane == 0) {
            logits[q] = pd + gate_b[0];
            invNqBuf[b * Q_ + q] = 1.0f / sqrtf(ps);
        }
    }
    __syncthreads();

    if (tid == 0) {
        float m = -1e30f;
        for (int q = 0; q < Q_; ++q) m = fmaxf(m, logits[q]);
        float e[Q_];
        float s = 0.f;
        for (int q = 0; q < Q_; ++q) { e[q] = expf(logits[q] - m); s += e[q]; }
        const float sc = out_w[0] * w2[0] / s;
        for (int q = 0; q < Q_; ++q) wqBuf[b * Q_ + q] = e[q] * sc;
    }
    if (tid < D_)
        score[b * D_ + tid] = out_w[0] * (w2[0] * b1[0] + b2[0]) + out_b[0];
}

// ---------------------------------------------------------------------------
// Kernel 2 (main): one lane per doc term.
//  - q rows staged ONCE per block into LDS, chunk-major [kc][q], pre-scaled
//    by 1/||q||  -> per-chunk reads are same-address ds_read_b128 broadcasts
//  - doc row streamed with a 15-deep rolling float4 register prefetch
//    (steady state ~15 outstanding global_load_dwordx4 per lane)
//  - binning: acc = dot(d, q_hat); compare acc against k*||d|| (no division)
// ---------------------------------------------------------------------------
__global__ __launch_bounds__(256) void drmm_main(
    const int* __restrict__ bq, const int* __restrict__ bdocs,
    const float* __restrict__ emb, const float* __restrict__ w1,
    const float* __restrict__ wqBuf, const float* __restrict__ invNqBuf,
    float* __restrict__ score)
{
    const int ls = blockIdx.x;   // l-split 0..3 (250 terms each)
    const int d  = blockIdx.y;
    const int b  = blockIdx.z;
    const int tid = threadIdx.x;

    __shared__ float4 qlds[NC * Q_];   // 19.2 KB, layout [kc][q]

    // ---- stage normalized q rows into LDS (contiguous per wave, no conflicts)
    for (int s = tid; s < NC * Q_; s += 256) {
        const int q = s & (Q_ - 1), kc = s >> 4;
        const int tok = bq[b * Q_ + q];
        const float inv = invNqBuf[b * Q_ + q];
        float4 v = *(const float4*)(emb + (size_t)tok * E_ + 4 * kc);
        v.x *= inv; v.y *= inv; v.z *= inv; v.w *= inv;
        qlds[s] = v;
    }
    __syncthreads();

    const float w10 = w1[0], w11 = w1[1], w12 = w1[2], w13 = w1[3], w14 = w1[4];

    float total = 0.f;
    if (tid < 250) {
        const int tok = bdocs[(b * D_ + d) * L_ + ls * 250 + tid];
        const float* drow = emb + (size_t)tok * E_;

        float acc[Q_];
#pragma unroll
        for (int q = 0; q < Q_; ++q) acc[q] = 0.f;
        float sq = 0.f;

        float4 buf[PF];
#pragma unroll
        for (int i = 0; i < PF; ++i) buf[i] = *(const float4*)(drow + 4 * i);

#pragma unroll 1
        for (int g = 0; g < 4; ++g) {          // groups 0..3 prefetch group g+1
#pragma unroll
            for (int i = 0; i < PF; ++i) {
                const float4 dv = buf[i];
                buf[i] = *(const float4*)(drow + 4 * ((g + 1) * PF + i));
                sq = fmaf(dv.x, dv.x, fmaf(dv.y, dv.y, fmaf(dv.z, dv.z, fmaf(dv.w, dv.w, sq))));
                const float4* qp = qlds + (g * PF + i) * Q_;
#pragma unroll
                for (int q = 0; q < Q_; ++q) {
                    const float4 qv = qp[q];   // broadcast ds_read_b128
                    acc[q] = fmaf(dv.w, qv.w, fmaf(dv.z, qv.z, fmaf(dv.y, qv.y, fmaf(dv.x, qv.x, acc[q]))));
                }
            }
        }
#pragma unroll
        for (int i = 0; i < PF; ++i) {         // tail group 4 (no prefetch)
            const float4 dv = buf[i];
            sq = fmaf(dv.x, dv.x, fmaf(dv.y, dv.y, fmaf(dv.z, dv.z, fmaf(dv.w, dv.w, sq))));
            const float4* qp = qlds + (4 * PF + i) * Q_;
#pragma unroll
            for (int q = 0; q < Q_; ++q) {
                const float4 qv = qp[q];
                acc[q] = fmaf(dv.w, qv.w, fmaf(dv.z, qv.z, fmaf(dv.y, qv.y, fmaf(dv.x, qv.x, acc[q]))));
            }
        }

        const float nd = sqrtf(sq);            // acc[q] = cos * nd
#pragma unroll
        for (int q = 0; q < Q_; ++q) {
            const float a = acc[q];
            const float wv = (a < -nd)        ? 0.f
                           : (a < -0.5f * nd) ? w10
                           : (a < 0.f)        ? w11
                           : (a < 0.5f * nd)  ? w12
                           : (a < nd)         ? w13
                           : (a <= nd)        ? w14
                                              : 0.f;
            total = fmaf(wqBuf[b * Q_ + q], wv, total);   // uniform -> s_load
        }
    }

    // block reduce: wave butterfly -> LDS -> one atomic
#pragma unroll
    for (int off = 32; off > 0; off >>= 1) total += __shfl_xor(total, off);
    __shared__ float wsum[4];
    if ((tid & 63) == 0) wsum[tid >> 6] = total;
    __syncthreads();
    if (tid == 0)
        atomicAdd(&score[b * D_ + d], wsum[0] + wsum[1] + wsum[2] + wsum[3]);
}

extern "C" void kernel_launch(void* const* d_in, const int* in_sizes, int n_in,
                              void* d_out, int out_size, void* d_ws, size_t ws_size,
                              hipStream_t stream)
{
    const int*   bq     = (const int*)d_in[0];
    const int*   bdocs  = (const int*)d_in[1];
    const float* emb    = (const float*)d_in[2];
    const float* gate_w = (const float*)d_in[3];
    const float* gate_b = (const float*)d_in[4];
    const float* w1     = (const float*)d_in[5];
    const float* b1     = (const float*)d_in[6];
    const float* w2     = (const float*)d_in[7];
    const float* b2     = (const float*)d_in[8];
    const float* out_w  = (const float*)d_in[9];
    const float* out_b  = (const float*)d_in[10];

    float* score  = (float*)d_out;
    float* wqBuf  = (float*)d_ws;          // 512 floats
    float* invNq  = wqBuf + B_ * Q_;       // 512 floats  (ws usage: 4 KiB)

    drmm_prep<<<dim3(B_), dim3(256), 0, stream>>>(
        bq, emb, gate_w, gate_b, b1, w2, b2, out_w, out_b, wqBuf, invNq, score);

    drmm_main<<<dim3(4, D_, B_), dim3(256), 0, stream>>>(
        bq, bdocs, emb, w1, wqBuf, invNq, score);
}

// Round 3
// 272.816 us; speedup vs baseline: 1.8559x; 1.8559x over previous
//
#include <hip/hip_runtime.h>
#include <math.h>

#define B_ 32
#define Q_ 16
#define D_ 10
#define L_ 1000
#define E_ 300
#define SEC 5          // sections per row
#define SF 15          // float4 chunks per section (5*15*4 = 300 floats)

// ---------------------------------------------------------------------------
// Kernel 1 (prep): gate logits -> softmax -> fused per-query weight
//   wq[b,q]    = softmax(gate_logits)[b,q] * out_w * w2
//   invNq[b,q] = 1/||emb[q_tok]||
//   score[b,d] = out_w*(w2*b1 + b2) + out_b   (atomics add onto this)
// ---------------------------------------------------------------------------
__global__ __launch_bounds__(256) void drmm_prep(
    const int* __restrict__ bq, const float* __restrict__ emb,
    const float* __restrict__ gate_w, const float* __restrict__ gate_b,
    const float* __restrict__ b1, const float* __restrict__ w2,
    const float* __restrict__ b2, const float* __restrict__ out_w,
    const float* __restrict__ out_b,
    float* __restrict__ wqBuf, float* __restrict__ invNqBuf,
    float* __restrict__ score)
{
    const int b = blockIdx.x;
    const int tid = threadIdx.x;
    const int w = tid >> 6, lane = tid & 63;
    __shared__ float logits[Q_];

#pragma unroll
    for (int i = 0; i < 4; ++i) {
        const int q = w * 4 + i;                  // 4 waves x 4 -> q = 0..15
        const int tok = bq[b * Q_ + q];
        const float* row = emb + (size_t)tok * E_;
        float4 dv = *(const float4*)(row + 4 * lane);
        float4 gv = *(const float4*)(gate_w + 4 * lane);
        float pd = dv.x * gv.x + dv.y * gv.y + dv.z * gv.z + dv.w * gv.w;
        float ps = dv.x * dv.x + dv.y * dv.y + dv.z * dv.z + dv.w * dv.w;
        if (lane < 11) {
            float4 dv2 = *(const float4*)(row + 256 + 4 * lane);
            float4 gv2 = *(const float4*)(gate_w + 256 + 4 * lane);
            pd += dv2.x * gv2.x + dv2.y * gv2.y + dv2.z * gv2.z + dv2.w * gv2.w;
            ps += dv2.x * dv2.x + dv2.y * dv2.y + dv2.z * dv2.z + dv2.w * dv2.w;
        }
#pragma unroll
        for (int off = 32; off > 0; off >>= 1) {
            pd += __shfl_xor(pd, off);
            ps += __shfl_xor(ps, off);
        }
        if (lane == 0) {
            logits[q] = pd + gate_b[0];
            invNqBuf[b * Q_ + q] = 1.0f / sqrtf(ps);
        }
    }
    __syncthreads();

    if (tid == 0) {
        float m = -1e30f;
        for (int q = 0; q < Q_; ++q) m = fmaxf(m, logits[q]);
        float e[Q_];
        float s = 0.f;
        for (int q = 0; q < Q_; ++q) { e[q] = expf(logits[q] - m); s += e[q]; }
        const float sc = out_w[0] * w2[0] / s;
        for (int q = 0; q < Q_; ++q) wqBuf[b * Q_ + q] = e[q] * sc;
    }
    if (tid < D_)
        score[b * D_ + tid] = out_w[0] * (w2[0] * b1[0] + b2[0]) + out_b[0];
}

// ---------------------------------------------------------------------------
// Kernel 2 (main): one lane per doc term, section-structured for concurrency:
//  - doc row: 5 sections x 15 float4; all 15 global_load_dwordx4 of a section
//    issued as an independent batch (imm offsets off one base -> 15 in flight)
//  - q rows: block-uniform -> s_load_dwordx4 batches of 15 per q, consumed by
//    v_fma with SGPR second operand. No LDS, no VGPR cost for q data. The
//    q-loop is fully unrolled so toks[q] stays constant-indexed in SGPRs;
//    next q's scalar loads overlap current q's 60 FMAs.
//  - normalization deferred to epilogue: a = dot*invNq, compare vs k*nd.
// ---------------------------------------------------------------------------
__global__ __launch_bounds__(256) void drmm_main(
    const int* __restrict__ bq, const int* __restrict__ bdocs,
    const float* __restrict__ emb, const float* __restrict__ w1,
    const float* __restrict__ wqBuf, const float* __restrict__ invNqBuf,
    float* __restrict__ score)
{
    const int ls = blockIdx.x;   // l-split 0..3 (250 terms each)
    const int d  = blockIdx.y;
    const int b  = blockIdx.z;
    const int tid = threadIdx.x;

    int toks[Q_];
#pragma unroll
    for (int q = 0; q < Q_; ++q) toks[q] = bq[b * Q_ + q];   // uniform -> SGPR

    float total = 0.f;
    if (tid < 250) {
        const int tok = bdocs[(b * D_ + d) * L_ + ls * 250 + tid];
        const float* drow = emb + (size_t)tok * E_;

        float acc[Q_];
#pragma unroll
        for (int q = 0; q < Q_; ++q) acc[q] = 0.f;
        float sq = 0.f;

#pragma unroll 1
        for (int s = 0; s < SEC; ++s) {
            const float* ds = drow + s * (SF * 4);
            float4 dv[SF];
#pragma unroll
            for (int i = 0; i < SF; ++i)
                dv[i] = *(const float4*)(ds + 4 * i);   // 15 vmem in flight
#pragma unroll
            for (int i = 0; i < SF; ++i)
                sq = fmaf(dv[i].x, dv[i].x, fmaf(dv[i].y, dv[i].y,
                     fmaf(dv[i].z, dv[i].z, fmaf(dv[i].w, dv[i].w, sq))));
#pragma unroll
            for (int q = 0; q < Q_; ++q) {
                const float* qs = emb + (size_t)toks[q] * E_ + s * (SF * 4);
                float a = acc[q];
#pragma unroll
                for (int i = 0; i < SF; ++i) {
                    const float4 qv = *(const float4*)(qs + 4 * i); // s_load_dwordx4
                    a = fmaf(dv[i].w, qv.w, fmaf(dv[i].z, qv.z,
                        fmaf(dv[i].y, qv.y, fmaf(dv[i].x, qv.x, a))));
                }
                acc[q] = a;
            }
        }

        const float nd = sqrtf(sq);
        const float w10 = w1[0], w11 = w1[1], w12 = w1[2], w13 = w1[3], w14 = w1[4];
#pragma unroll
        for (int q = 0; q < Q_; ++q) {
            const float a = acc[q] * invNqBuf[b * Q_ + q];  // = dot/nq
            const float wv = (a < -nd)        ? 0.f
                           : (a < -0.5f * nd) ? w10
                           : (a < 0.f)        ? w11
                           : (a < 0.5f * nd)  ? w12
                           : (a < nd)         ? w13
                           : (a <= nd)        ? w14
                                              : 0.f;
            total = fmaf(wqBuf[b * Q_ + q], wv, total);     // uniform s_loads
        }
    }

    // block reduce: wave butterfly -> LDS -> one atomic
#pragma unroll
    for (int off = 32; off > 0; off >>= 1) total += __shfl_xor(total, off);
    __shared__ float wsum[4];
    if ((tid & 63) == 0) wsum[tid >> 6] = total;
    __syncthreads();
    if (tid == 0)
        atomicAdd(&score[b * D_ + d], wsum[0] + wsum[1] + wsum[2] + wsum[3]);
}

extern "C" void kernel_launch(void* const* d_in, const int* in_sizes, int n_in,
                              void* d_out, int out_size, void* d_ws, size_t ws_size,
                              hipStream_t stream)
{
    const int*   bq     = (const int*)d_in[0];
    const int*   bdocs  = (const int*)d_in[1];
    const float* emb    = (const float*)d_in[2];
    const float* gate_w = (const float*)d_in[3];
    const float* gate_b = (const float*)d_in[4];
    const float* w1     = (const float*)d_in[5];
    const float* b1     = (const float*)d_in[6];
    const float* w2     = (const float*)d_in[7];
    const float* b2     = (const float*)d_in[8];
    const float* out_w  = (const float*)d_in[9];
    const float* out_b  = (const float*)d_in[10];

    float* score  = (float*)d_out;
    float* wqBuf  = (float*)d_ws;          // 512 floats
    float* invNq  = wqBuf + B_ * Q_;       // 512 floats  (ws usage: 4 KiB)

    drmm_prep<<<dim3(B_), dim3(256), 0, stream>>>(
        bq, emb, gate_w, gate_b, b1, w2, b2, out_w, out_b, wqBuf, invNq, score);

    drmm_main<<<dim3(4, D_, B_), dim3(256), 0, stream>>>(
        bq, bdocs, emb, w1, wqBuf, invNq, score);
}